// Round 16
// baseline (182.027 us; speedup 1.0000x reference)
//
#include <hip/hip_runtime.h>
#include <hip/hip_bf16.h>

#define DIM 1024
#define NUM_HEADS 16
#define HEAD_DIM 64
#define BATCH 2
#define SEQ 2048
#define M_ROWS (BATCH * SEQ)   // 4096

typedef short bh8 __attribute__((ext_vector_type(8)));   // 8 bf16 (4 VGPRs)
typedef float f32x4 __attribute__((ext_vector_type(4)));
typedef float f32x16 __attribute__((ext_vector_type(16)));

#define SCALE_Q 0.18033688011116016f   // 0.125 * log2(e), folded into Q projection

#define MFMA16(a, b, c) __builtin_amdgcn_mfma_f32_16x16x32_bf16(a, b, c, 0, 0, 0)
#define MFMA32(a, b, c) __builtin_amdgcn_mfma_f32_32x32x16_bf16(a, b, c, 0, 0, 0)

#if __has_builtin(__builtin_amdgcn_exp2f)
#define EXP2F(x) __builtin_amdgcn_exp2f(x)
#else
#define EXP2F(x) exp2f(x)
#endif

__device__ __forceinline__ ushort f2bf(float f) {
    union { float f; unsigned u; } v; v.f = f;
    unsigned u = v.u;
    unsigned r = (u + 0x7FFFu + ((u >> 16) & 1u)) >> 16;
    return (ushort)r;
}

// m240: no cvt_pk builtin on gfx950 -> inline asm (RNE pack of 2 f32 -> 2 bf16)
__device__ __forceinline__ unsigned cvt_pk_bf16(float lo, float hi) {
    unsigned r;
    asm("v_cvt_pk_bf16_f32 %0, %1, %2" : "=v"(r) : "v"(lo), "v"(hi));
    return r;
}

// out0 = {lanes0-31: a(own), lanes32-63: b(from lanes0-31)}
// out1 = {lanes0-31: a(from lanes32-63), lanes32-63: b(own)}
__device__ __forceinline__ void plane_swap(unsigned a, unsigned b,
                                           unsigned& o0, unsigned& o1, int h) {
#if __has_builtin(__builtin_amdgcn_permlane32_swap)
    (void)h;
    auto pr = __builtin_amdgcn_permlane32_swap(a, b, false, false);
    unsigned o[2]; __builtin_memcpy(o, &pr, 8);
    o0 = o[0]; o1 = o[1];
#else
    unsigned sa = (unsigned)__shfl_xor((int)a, 32);
    unsigned sb = (unsigned)__shfl_xor((int)b, 32);
    o0 = h ? sb : a;
    o1 = h ? b : sa;
#endif
}

// async global->LDS 16B copy; LDS dest is wave-uniform base + lane*16
__device__ __forceinline__ void async_cp16(const ushort* g, ushort* l) {
    __builtin_amdgcn_global_load_lds(
        (const __attribute__((address_space(1))) void*)(uintptr_t)g,
        (__attribute__((address_space(3))) void*)(uint32_t)(uintptr_t)l,
        16, 0, 0);
}

// ------- fused prep: z<4 -> transpose+cast W_z [K,N]->[N,K] bf16; z==4 -> cast x -------
__global__ __launch_bounds__(256) void prep_inputs(
    const float* __restrict__ W0, const float* __restrict__ W1,
    const float* __restrict__ W2, const float* __restrict__ W3,
    const float* __restrict__ x,
    ushort* __restrict__ T0, ushort* __restrict__ T1,
    ushort* __restrict__ T2, ushort* __restrict__ T3,
    ushort* __restrict__ xb)
{
    const int z = blockIdx.z;
    const int t = threadIdx.x;
    if (z == 4) {
        int base = (blockIdx.y * 32 + blockIdx.x) * 1024 + t;   // float4 index
        const float4* in4 = (const float4*)x;
        ushort4* out4 = (ushort4*)xb;
        #pragma unroll
        for (int i = 0; i < 4; ++i) {
            float4 v = in4[base + i * 256];
            ushort4 o;
            o.x = f2bf(v.x); o.y = f2bf(v.y); o.z = f2bf(v.z); o.w = f2bf(v.w);
            out4[base + i * 256] = o;
        }
        return;
    }
    __shared__ float tile[32][33];
    const float* W = (z == 0) ? W0 : (z == 1) ? W1 : (z == 2) ? W2 : W3;
    ushort* Wt = (z == 0) ? T0 : (z == 1) ? T1 : (z == 2) ? T2 : T3;
    const int tx = t & 31, ty = t >> 5;            // ty 0..7
    const int k0 = blockIdx.y * 32, n0 = blockIdx.x * 32;
    #pragma unroll
    for (int i = 0; i < 4; ++i)
        tile[ty + 8 * i][tx] = W[(size_t)(k0 + ty + 8 * i) * DIM + n0 + tx];
    __syncthreads();
    #pragma unroll
    for (int i = 0; i < 4; ++i)
        Wt[(size_t)(n0 + ty + 8 * i) * DIM + k0 + tx] = f2bf(tile[tx][ty + 8 * i]);
}

// ---------------- z-FUSED QKV projection: 128x64 tile x 3 outputs, BK=128 ------------
// (R15-proven: fused A pass + BK=128 halves barrier drains; 177.8us total)
__global__ __launch_bounds__(512, 4) void gemm_qkv(
    const ushort* __restrict__ A,
    const ushort* __restrict__ WqT, const ushort* __restrict__ WkT,
    const ushort* __restrict__ WvT,
    const float* __restrict__ bq, const float* __restrict__ bk,
    const float* __restrict__ bv,
    ushort* __restrict__ qo, ushort* __restrict__ ko_, ushort* __restrict__ vo)
{
    __shared__ ushort smem[40960];   // 80 KB: As 128x128=16384, Bs[3] 64x128=8192 each
    ushort* As  = smem;
    ushort* Bs0 = smem + 16384;
    ushort* Bs1 = smem + 24576;
    ushort* Bs2 = smem + 32768;

    const int lin = blockIdx.x + 16 * blockIdx.y;   // [0,512)
    const int swz = (lin & 7) * 64 + (lin >> 3);    // bijective XCD chunks
    const int bx = swz & 15, by = swz >> 4;

    const int t = threadIdx.x;                      // 0..511
    const int lane = t & 63, wave = t >> 6;         // wave 0..7
    const int col = lane & 15, quad = lane >> 4;
    const int m0 = by * 128, n0 = bx * 64;
    const int wm = (wave & 3) * 32, wn = (wave >> 2) * 32;

    f32x4 acc[3][2][2] = {};

    for (int k0 = 0; k0 < DIM; k0 += 128) {
        __syncthreads();
        #pragma unroll
        for (int j = 0; j < 4; ++j) {               // A: 2048 chunks, 4 issues/wave
            int C = wave * 256 + j * 64 + lane;
            int row = C >> 4;
            int lch = (C & 15) ^ (row & 7);
            async_cp16(&A[(size_t)(m0 + row) * DIM + k0 + lch * 8],
                       &As[(wave * 256 + j * 64) * 8]);
        }
        #pragma unroll
        for (int j = 0; j < 2; ++j) {               // B: 1024 chunks each, 2 issues/wave
            int C = wave * 128 + j * 64 + lane;
            int row = C >> 4;
            int lch = (C & 15) ^ (row & 7);
            size_t goff = (size_t)(n0 + row) * DIM + k0 + lch * 8;
            async_cp16(&WqT[goff], &Bs0[(wave * 128 + j * 64) * 8]);
            async_cp16(&WkT[goff], &Bs1[(wave * 128 + j * 64) * 8]);
            async_cp16(&WvT[goff], &Bs2[(wave * 128 + j * 64) * 8]);
        }
        __syncthreads();
        #pragma unroll
        for (int kk = 0; kk < 4; ++kk) {
            bh8 af[2];
            #pragma unroll
            for (int mi = 0; mi < 2; ++mi) {
                int row = wm + mi * 16 + col;
                af[mi] = *(const bh8*)&As[row * 128 + (((kk * 4 + quad) ^ (row & 7)) * 8)];
            }
            const ushort* Bsz[3] = { Bs0, Bs1, Bs2 };
            #pragma unroll
            for (int z = 0; z < 3; ++z) {
                bh8 bfr[2];
                #pragma unroll
                for (int ni = 0; ni < 2; ++ni) {
                    int row = wn + ni * 16 + col;
                    bfr[ni] = *(const bh8*)&Bsz[z][row * 128 + (((kk * 4 + quad) ^ (row & 7)) * 8)];
                }
                #pragma unroll
                for (int mi = 0; mi < 2; ++mi)
                    #pragma unroll
                    for (int ni = 0; ni < 2; ++ni)
                        acc[z][mi][ni] = MFMA16(af[mi], bfr[ni], acc[z][mi][ni]);
            }
        }
    }

    const int b = m0 >> 11, s0 = m0 & (SEQ - 1);
    const int h = bx;                               // n0>>6

    #pragma unroll
    for (int z = 0; z < 3; ++z) {                   // FULL unroll: static acc[z] index
        const float* bias = (z == 0) ? bq : (z == 1) ? bk : bv;
        ushort* outp = (z == 0) ? qo : (z == 1) ? ko_ : vo;
        __syncthreads();                            // prev phase reads / core reads done
        if (z < 2) {
            const float scl = (z == 0) ? SCALE_Q : 1.f;
            ushort* LT = smem;                      // 128 x 72
            #pragma unroll
            for (int mi = 0; mi < 2; ++mi)
                #pragma unroll
                for (int ni = 0; ni < 2; ++ni) {
                    int dl = wn + ni * 16 + col;
                    float bvv = bias[n0 + dl];
                    #pragma unroll
                    for (int r = 0; r < 4; ++r) {
                        int ml = wm + mi * 16 + quad * 4 + r;
                        LT[ml * 72 + dl] = f2bf((acc[z][mi][ni][r] + bvv) * scl);
                    }
                }
            __syncthreads();
            ushort* Cp = outp + (((size_t)(b * NUM_HEADS + h) * SEQ + s0) << 6);
            #pragma unroll
            for (int i = 0; i < 2; ++i) {
                int c = i * 512 + t;                // 1024 chunks of 8
                int row = c >> 3, ko = (c & 7) * 8;
                *(uint4*)&Cp[row * 64 + ko] = *(const uint4*)&LT[row * 72 + ko];
            }
        } else {
            // V transposed [B,H,64,S] via LDS transpose
            ushort* LT = smem;                      // 64 x 136
            #pragma unroll
            for (int mi = 0; mi < 2; ++mi)
                #pragma unroll
                for (int ni = 0; ni < 2; ++ni) {
                    int nl = wn + ni * 16 + col;
                    float bvv = bias[n0 + nl];
                    #pragma unroll
                    for (int r = 0; r < 4; ++r) {
                        int ml = wm + mi * 16 + quad * 4 + r;
                        LT[nl * 136 + ml] = f2bf(acc[z][mi][ni][r] + bvv);
                    }
                }
            __syncthreads();
            ushort* Cp = outp + (((size_t)(b * NUM_HEADS + h) * HEAD_DIM) << 11);
            #pragma unroll
            for (int i = 0; i < 2; ++i) {
                int c = i * 512 + t;                // 1024 chunks of 8
                int row = c >> 4, mo = (c & 15) * 8;
                *(uint4*)&Cp[((size_t)row << 11) + s0 + mo] = *(const uint4*)&LT[row * 136 + mo];
            }
        }
    }
}

// ---------------- gemm_out core: 128x64 tile, BK=128 (R15-pattern swizzle) ------------
// 8 K-steps instead of 16 -> half the vmcnt(0)+barrier drains. LDS 48KB (A 32 + B 16),
// grid 512 = 2 blocks/CU (LDS cap 3, unaffected).
#define GTM 128
#define GTN 64

__device__ __forceinline__ void gemm_core(
    const ushort* __restrict__ A, const ushort* __restrict__ Bt,
    ushort* smem, int m0, int n0, int t, f32x4 acc[4][2])
{
    ushort* As = smem;          // 128*128 = 16384 ushorts (32 KB)
    ushort* Bs = smem + 16384;  //  64*128 =  8192 ushorts (16 KB)
    const int lane = t & 63, wave = t >> 6;
    const int col = lane & 15, quad = lane >> 4;
    const int wm = (wave & 1) * 64, wn = (wave >> 1) * 32;

    for (int k0 = 0; k0 < DIM; k0 += 128) {
        __syncthreads();
        #pragma unroll
        for (int j = 0; j < 8; ++j) {               // A: 2048 chunks, 8 issues/wave
            int C = wave * 512 + j * 64 + lane;
            int row = C >> 4;
            int lch = (C & 15) ^ (row & 7);
            async_cp16(&A[(size_t)(m0 + row) * DIM + k0 + lch * 8],
                       &As[(wave * 512 + j * 64) * 8]);
        }
        #pragma unroll
        for (int j = 0; j < 4; ++j) {               // B: 1024 chunks, 4 issues/wave
            int C = wave * 256 + j * 64 + lane;
            int row = C >> 4;
            int lch = (C & 15) ^ (row & 7);
            async_cp16(&Bt[(size_t)(n0 + row) * DIM + k0 + lch * 8],
                       &Bs[(wave * 256 + j * 64) * 8]);
        }
        __syncthreads();
        #pragma unroll
        for (int kk = 0; kk < 4; ++kk) {
            bh8 af[4], bfr[2];
            #pragma unroll
            for (int mi = 0; mi < 4; ++mi) {
                int row = wm + mi * 16 + col;
                af[mi] = *(const bh8*)&As[row * 128 + (((kk * 4 + quad) ^ (row & 7)) * 8)];
            }
            #pragma unroll
            for (int ni = 0; ni < 2; ++ni) {
                int row = wn + ni * 16 + col;
                bfr[ni] = *(const bh8*)&Bs[row * 128 + (((kk * 4 + quad) ^ (row & 7)) * 8)];
            }
            #pragma unroll
            for (int mi = 0; mi < 4; ++mi)
                #pragma unroll
                for (int ni = 0; ni < 2; ++ni)
                    acc[mi][ni] = MFMA16(af[mi], bfr[ni], acc[mi][ni]);
        }
    }
}

// ---------------- output projection: fp32 out (XCD-swizzled, BK=128) ------------------
__global__ __launch_bounds__(256) void gemm_out(
    const ushort* __restrict__ A, const ushort* __restrict__ Bt,
    const float* __restrict__ bias, float* __restrict__ C)
{
    __shared__ ushort smem[24576];   // 48 KB
    const int lin = blockIdx.x + 16 * blockIdx.y;   // [0,512)
    const int swz = (lin & 7) * 64 + (lin >> 3);    // bijective
    const int bx = swz & 15, by = swz >> 4;

    const int t = threadIdx.x;
    const int lane = t & 63, wave = t >> 6;
    const int col = lane & 15, quad = lane >> 4;
    const int m0 = by * GTM, n0 = bx * GTN;
    const int wm = (wave & 1) * 64, wn = (wave >> 1) * 32;
    f32x4 acc[4][2] = {};

    gemm_core(A, Bt, smem, m0, n0, t, acc);

    #pragma unroll
    for (int mi = 0; mi < 4; ++mi)
        #pragma unroll
        for (int ni = 0; ni < 2; ++ni) {
            int n = n0 + wn + ni * 16 + col;
            float bvv = bias[n];
            #pragma unroll
            for (int r = 0; r < 4; ++r) {
                int m = m0 + wm + mi * 16 + quad * 4 + r;
                C[(size_t)m * DIM + n] = acc[mi][ni][r] + bvv;
            }
        }
}

// ---------------- MFMA flash attention: R9-exact (best measured: 48.3-48.8us) --------
__global__ __launch_bounds__(256, 2) void attn_mfma(
    const ushort* __restrict__ Qg, const ushort* __restrict__ Kg,
    const ushort* __restrict__ Vtg, ushort* __restrict__ ctx)
{
    __shared__ char smem[34304];
    float* OA   = (float*)smem;                    // 64x65 f32 = 16640 B
    float* OB   = (float*)(smem + 16640);          // 64x65 f32
    float* lbuf = (float*)(smem + 33280);          // 4x64 f32

    const int t = threadIdx.x;
    const int lane = t & 63, wave = t >> 6;
    const int q32 = lane & 31, h = lane >> 5;      // lane column / half
    const int bh = blockIdx.x & 31;                // fast: bh b -> XCD b%8 (K/V L2-local)
    const int qt = 31 - (blockIdx.x >> 5);         // slow, descending: LPT
    const int b = bh >> 4, hd = bh & 15;
    const int q0 = qt << 6;
    const int kw0 = wave * 32;                     // wave's key offset in 128-span
    const ushort* Kp = Kg + ((size_t)bh << 17);
    const ushort* Vp = Vtg + ((size_t)bh << 17);
    const ushort* Qp = Qg + ((size_t)bh << 17);

    // Q fragments (B-operand): [qti][kc], pre-scaled by 0.125*log2e
    bh8 qf[2][4];
    #pragma unroll
    for (int qti = 0; qti < 2; ++qti)
        #pragma unroll
        for (int kc = 0; kc < 4; ++kc)
            qf[qti][kc] = *(const bh8*)&Qp[((size_t)(q0 + qti * 32 + q32) << 6)
                                           + kc * 16 + h * 8];

    f32x16 O[2][2] = {};                           // [qti][dti]: C col=q, row=d
    float l[2] = {0.f, 0.f};
    const int nIter = (q0 + 191) >> 7;             // ceil((q0+64)/128)

    // prologue: load iter-0 K/V into next-buffers
    bh8 kf_n[4], vf_n[2][2];
    #pragma unroll
    for (int kc = 0; kc < 4; ++kc)
        kf_n[kc] = *(const bh8*)&Kp[((size_t)(kw0 + q32) << 6) + kc * 16 + h * 8];
    #pragma unroll
    for (int dti = 0; dti < 2; ++dti)
        #pragma unroll
        for (int kc = 0; kc < 2; ++kc)
            vf_n[dti][kc] = *(const bh8*)&Vp[((size_t)(dti * 32 + q32) << 11)
                                             + kw0 + kc * 16 + h * 8];

    #pragma unroll 1
    for (int it = 0; it < nIter; ++it) {
        const int kb = it << 7;
        if (kb + kw0 > q0 + 63) break;             // once masked, always masked

        // rotate buffers (register renames, free)
        bh8 kf[4], vf[2][2];
        #pragma unroll
        for (int kc = 0; kc < 4; ++kc) kf[kc] = kf_n[kc];
        #pragma unroll
        for (int dti = 0; dti < 2; ++dti) {
            vf[dti][0] = vf_n[dti][0]; vf[dti][1] = vf_n[dti][1];
        }

        // issue ALL it+1 prefetches NOW -> full-iteration issue->consume distance
        const int kb2 = kb + 128;
        if (it + 1 < nIter) {
            #pragma unroll
            for (int kc = 0; kc < 4; ++kc)
                kf_n[kc] = *(const bh8*)&Kp[((size_t)(kb2 + kw0 + q32) << 6)
                                            + kc * 16 + h * 8];
            #pragma unroll
            for (int dti = 0; dti < 2; ++dti)
                #pragma unroll
                for (int kc = 0; kc < 2; ++kc)
                    vf_n[dti][kc] = *(const bh8*)&Vp[((size_t)(dti * 32 + q32) << 11)
                                                     + kb2 + kw0 + kc * 16 + h * 8];
        }

        // St = K_w @ Q^T per 32-q tile: C col=q32, row=key (r&3)+8*(r>>2)+4h
        f32x16 St[2] = {};
        __builtin_amdgcn_s_setprio(1);
        #pragma unroll
        for (int kc = 0; kc < 4; ++kc) {
            St[0] = MFMA32(kf[kc], qf[0][kc], St[0]);
            St[1] = MFMA32(kf[kc], qf[1][kc], St[1]);
        }
        __builtin_amdgcn_s_setprio(0);

        // causal mask (only near the diagonal)
        if (kb + kw0 + 31 > q0) {
            #pragma unroll
            for (int qti = 0; qti < 2; ++qti) {
                int q_abs = q0 + qti * 32 + q32;
                #pragma unroll
                for (int r = 0; r < 16; ++r) {
                    int key_abs = kb + kw0 + (r & 3) + ((r >> 2) << 3) + 4 * h;
                    if (key_abs > q_abs) St[qti][r] = -1e30f;
                }
            }
        }

        // exp2 (Q pre-scaled) -> pack bf16 -> permlane32_swap -> PV B-operand
        #pragma unroll
        for (int qti = 0; qti < 2; ++qti) {
            float p[16];
            #pragma unroll
            for (int r = 0; r < 16; ++r) p[r] = EXP2F(St[qti][r]);
            float t0 = (p[0] + p[1]) + (p[2] + p[3]);
            float t1 = (p[4] + p[5]) + (p[6] + p[7]);
            float t2 = (p[8] + p[9]) + (p[10] + p[11]);
            float t3 = (p[12] + p[13]) + (p[14] + p[15]);
            l[qti] += (t0 + t1) + (t2 + t3);

            unsigned w[8];
            #pragma unroll
            for (int m = 0; m < 8; ++m) w[m] = cvt_pk_bf16(p[2 * m], p[2 * m + 1]);
            unsigned j0, j1, j2, j3, j4, j5, j6, j7;
            plane_swap(w[0], w[2], j0, j2, h);     // keys 0-15  -> B-words 0..3
            plane_swap(w[1], w[3], j1, j3, h);
            plane_swap(w[4], w[6], j4, j6, h);     // keys 16-31 -> B-words 0..3
            plane_swap(w[5], w[7], j5, j7, h);
            union { unsigned u[4]; bh8 v; } pu0, pu1;
            pu0.u[0] = j0; pu0.u[1] = j1; pu0.u[2] = j2; pu0.u[3] = j3;
            pu1.u[0] = j4; pu1.u[1] = j5; pu1.u[2] = j6; pu1.u[3] = j7;

            // O[qti][dti] += V_w^T @ P (A=V^T from regs, B=P in regs; C col=q, row=d)
            __builtin_amdgcn_s_setprio(1);
            O[qti][0] = MFMA32(vf[0][0], pu0.v, O[qti][0]);
            O[qti][1] = MFMA32(vf[1][0], pu0.v, O[qti][1]);
            O[qti][0] = MFMA32(vf[0][1], pu1.v, O[qti][0]);
            O[qti][1] = MFMA32(vf[1][1], pu1.v, O[qti][1]);
            __builtin_amdgcn_s_setprio(0);
        }
    }

    // ----- epilogue: cross-wave reduction -----
    l[0] += __shfl_xor(l[0], 32);
    l[1] += __shfl_xor(l[1], 32);
    if (lane < 32) {
        lbuf[wave * 64 + q32]      = l[0];
        lbuf[wave * 64 + 32 + q32] = l[1];
    }
    __syncthreads();   // #1: l published

    if (wave == 1 || wave == 3) {
        float* dst = (wave == 1) ? OA : OB;
        #pragma unroll
        for (int qti = 0; qti < 2; ++qti)
            #pragma unroll
            for (int dti = 0; dti < 2; ++dti)
                #pragma unroll
                for (int r = 0; r < 16; ++r) {
                    int d_l = dti * 32 + (r & 3) + ((r >> 2) << 3) + 4 * h;
                    dst[d_l * 65 + qti * 32 + q32] = O[qti][dti][r];
                }
    }
    __syncthreads();   // #2
    if (wave == 0 || wave == 2) {
        float* src = (wave == 0) ? OA : OB;
        #pragma unroll
        for (int qti = 0; qti < 2; ++qti)
            #pragma unroll
            for (int dti = 0; dti < 2; ++dti)
                #pragma unroll
                for (int r = 0; r < 16; ++r) {
                    int d_l = dti * 32 + (r & 3) + ((r >> 2) << 3) + 4 * h;
                    O[qti][dti][r] += src[d_l * 65 + qti * 32 + q32];
                }
    }
    __syncthreads();   // #3
    if (wave == 2) {
        #pragma unroll
        for (int qti = 0; qti < 2; ++qti)
            #pragma unroll
            for (int dti = 0; dti < 2; ++dti)
                #pragma unroll
                for (int r = 0; r < 16; ++r) {
                    int d_l = dti * 32 + (r & 3) + ((r >> 2) << 3) + 4 * h;
                    OA[d_l * 65 + qti * 32 + q32] = O[qti][dti][r];
                }
    }
    __syncthreads();   // #4
    if (wave == 0) {
        float tot0 = lbuf[q32] + lbuf[64 + q32] + lbuf[128 + q32] + lbuf[192 + q32];
        float tot1 = lbuf[32 + q32] + lbuf[96 + q32] + lbuf[160 + q32] + lbuf[224 + q32];
        float inv0 = 1.f / tot0, inv1 = 1.f / tot1;
        ushort* Oq = (ushort*)(smem + 16640);      // 64 x 72 ushorts (reuse OB)
        #pragma unroll
        for (int qti = 0; qti < 2; ++qti) {
            float invq = qti ? inv1 : inv0;
            int qrow = qti * 32 + q32;
            #pragma unroll
            for (int dti = 0; dti < 2; ++dti)
                #pragma unroll
                for (int rg = 0; rg < 4; ++rg) {
                    int d0 = dti * 32 + rg * 8 + 4 * h;
                    float s0 = (O[qti][dti][rg * 4 + 0] + OA[(d0 + 0) * 65 + qrow]) * invq;
                    float s1 = (O[qti][dti][rg * 4 + 1] + OA[(d0 + 1) * 65 + qrow]) * invq;
                    float s2 = (O[qti][dti][rg * 4 + 2] + OA[(d0 + 2) * 65 + qrow]) * invq;
                    float s3 = (O[qti][dti][rg * 4 + 3] + OA[(d0 + 3) * 65 + qrow]) * invq;
                    uint2 pk; pk.x = cvt_pk_bf16(s0, s1); pk.y = cvt_pk_bf16(s2, s3);
                    *(uint2*)&Oq[qrow * 72 + d0] = pk;
                }
        }
        // coalesced 16B stores: 512 chunks of 8 ushorts, 8 per lane
        #pragma unroll
        for (int i = 0; i < 8; ++i) {
            int c = i * 64 + lane;
            int row = c >> 3, ko = (c & 7) * 8;
            *(uint4*)&ctx[((size_t)(b * SEQ) + q0 + row) * DIM + (hd << 6) + ko] =
                *(const uint4*)&Oq[row * 72 + ko];
        }
    }
}

// ---------------- launch ----------------
extern "C" void kernel_launch(void* const* d_in, const int* in_sizes, int n_in,
                              void* d_out, int out_size, void* d_ws, size_t ws_size,
                              hipStream_t stream) {
    const float* x  = (const float*)d_in[0];
    const float* Wq = (const float*)d_in[1];
    const float* bq = (const float*)d_in[2];
    const float* Wk = (const float*)d_in[3];
    const float* bk = (const float*)d_in[4];
    const float* Wv = (const float*)d_in[5];
    const float* bv = (const float*)d_in[6];
    const float* Wo = (const float*)d_in[7];
    const float* bo = (const float*)d_in[8];
    float* out = (float*)d_out;

    ushort* x_bf   = (ushort*)d_ws;              // 4M elems
    ushort* wq_t   = x_bf + 4194304;             // 1M each
    ushort* wk_t   = wq_t + 1048576;
    ushort* wv_t   = wk_t + 1048576;
    ushort* wo_t   = wv_t + 1048576;
    ushort* q_ws   = wo_t + 1048576;             // [B,H,S,64] 4M (pre-scaled)
    ushort* k_ws   = q_ws + 4194304;
    ushort* vt_ws  = k_ws + 4194304;             // [B,H,64,S] 4M
    ushort* ctx_ws = vt_ws + 4194304;            // [B,S,DIM]  4M

    dim3 pgrid(32, 32, 5);
    prep_inputs<<<pgrid, 256, 0, stream>>>(Wq, Wk, Wv, Wo, x,
                                           wq_t, wk_t, wv_t, wo_t, x_bf);

    dim3 qkv_grid(16, 32);                       // 512 blocks, z-fused, BK=128
    gemm_qkv<<<qkv_grid, 512, 0, stream>>>(x_bf, wq_t, wk_t, wv_t,
                                           bq, bk, bv, q_ws, k_ws, vt_ws);

    attn_mfma<<<1024, 256, 0, stream>>>(q_ws, k_ws, vt_ws, ctx_ws);

    dim3 ogrid(DIM / GTN, M_ROWS / GTM);         // (16, 32)
    gemm_out<<<ogrid, 256, 0, stream>>>(ctx_ws, wo_t, bo, out);
}

// Round 17
// 176.073 us; speedup vs baseline: 1.0338x; 1.0338x over previous
//
#include <hip/hip_runtime.h>
#include <hip/hip_bf16.h>

#define DIM 1024
#define NUM_HEADS 16
#define HEAD_DIM 64
#define BATCH 2
#define SEQ 2048
#define M_ROWS (BATCH * SEQ)   // 4096

typedef short bh8 __attribute__((ext_vector_type(8)));   // 8 bf16 (4 VGPRs)
typedef float f32x4 __attribute__((ext_vector_type(4)));
typedef float f32x16 __attribute__((ext_vector_type(16)));

#define SCALE_Q 0.18033688011116016f   // 0.125 * log2(e), folded into Q projection

#define MFMA16(a, b, c) __builtin_amdgcn_mfma_f32_16x16x32_bf16(a, b, c, 0, 0, 0)
#define MFMA32(a, b, c) __builtin_amdgcn_mfma_f32_32x32x16_bf16(a, b, c, 0, 0, 0)

#if __has_builtin(__builtin_amdgcn_exp2f)
#define EXP2F(x) __builtin_amdgcn_exp2f(x)
#else
#define EXP2F(x) exp2f(x)
#endif

__device__ __forceinline__ ushort f2bf(float f) {
    union { float f; unsigned u; } v; v.f = f;
    unsigned u = v.u;
    unsigned r = (u + 0x7FFFu + ((u >> 16) & 1u)) >> 16;
    return (ushort)r;
}

// m240: no cvt_pk builtin on gfx950 -> inline asm (RNE pack of 2 f32 -> 2 bf16)
__device__ __forceinline__ unsigned cvt_pk_bf16(float lo, float hi) {
    unsigned r;
    asm("v_cvt_pk_bf16_f32 %0, %1, %2" : "=v"(r) : "v"(lo), "v"(hi));
    return r;
}

// out0 = {lanes0-31: a(own), lanes32-63: b(from lanes0-31)}
// out1 = {lanes0-31: a(from lanes32-63), lanes32-63: b(own)}
__device__ __forceinline__ void plane_swap(unsigned a, unsigned b,
                                           unsigned& o0, unsigned& o1, int h) {
#if __has_builtin(__builtin_amdgcn_permlane32_swap)
    (void)h;
    auto pr = __builtin_amdgcn_permlane32_swap(a, b, false, false);
    unsigned o[2]; __builtin_memcpy(o, &pr, 8);
    o0 = o[0]; o1 = o[1];
#else
    unsigned sa = (unsigned)__shfl_xor((int)a, 32);
    unsigned sb = (unsigned)__shfl_xor((int)b, 32);
    o0 = h ? sb : a;
    o1 = h ? b : sa;
#endif
}

// async global->LDS 16B copy; LDS dest is wave-uniform base + lane*16
__device__ __forceinline__ void async_cp16(const ushort* g, ushort* l) {
    __builtin_amdgcn_global_load_lds(
        (const __attribute__((address_space(1))) void*)(uintptr_t)g,
        (__attribute__((address_space(3))) void*)(uint32_t)(uintptr_t)l,
        16, 0, 0);
}

// ------- fused prep: z<4 -> transpose+cast W_z [K,N]->[N,K] bf16; z==4 -> cast x -------
__global__ __launch_bounds__(256) void prep_inputs(
    const float* __restrict__ W0, const float* __restrict__ W1,
    const float* __restrict__ W2, const float* __restrict__ W3,
    const float* __restrict__ x,
    ushort* __restrict__ T0, ushort* __restrict__ T1,
    ushort* __restrict__ T2, ushort* __restrict__ T3,
    ushort* __restrict__ xb)
{
    const int z = blockIdx.z;
    const int t = threadIdx.x;
    if (z == 4) {
        int base = (blockIdx.y * 32 + blockIdx.x) * 1024 + t;   // float4 index
        const float4* in4 = (const float4*)x;
        ushort4* out4 = (ushort4*)xb;
        #pragma unroll
        for (int i = 0; i < 4; ++i) {
            float4 v = in4[base + i * 256];
            ushort4 o;
            o.x = f2bf(v.x); o.y = f2bf(v.y); o.z = f2bf(v.z); o.w = f2bf(v.w);
            out4[base + i * 256] = o;
        }
        return;
    }
    __shared__ float tile[32][33];
    const float* W = (z == 0) ? W0 : (z == 1) ? W1 : (z == 2) ? W2 : W3;
    ushort* Wt = (z == 0) ? T0 : (z == 1) ? T1 : (z == 2) ? T2 : T3;
    const int tx = t & 31, ty = t >> 5;            // ty 0..7
    const int k0 = blockIdx.y * 32, n0 = blockIdx.x * 32;
    #pragma unroll
    for (int i = 0; i < 4; ++i)
        tile[ty + 8 * i][tx] = W[(size_t)(k0 + ty + 8 * i) * DIM + n0 + tx];
    __syncthreads();
    #pragma unroll
    for (int i = 0; i < 4; ++i)
        Wt[(size_t)(n0 + ty + 8 * i) * DIM + k0 + tx] = f2bf(tile[tx][ty + 8 * i]);
}

// ---------------- z-FUSED QKV projection: 128x64 tile x 3 outputs, BK=128 ------------
// (R15-proven: fused A pass + BK=128 halves barrier drains; VGPR-capped residency so
// 80KB LDS is free. 177.8us total.)
__global__ __launch_bounds__(512, 4) void gemm_qkv(
    const ushort* __restrict__ A,
    const ushort* __restrict__ WqT, const ushort* __restrict__ WkT,
    const ushort* __restrict__ WvT,
    const float* __restrict__ bq, const float* __restrict__ bk,
    const float* __restrict__ bv,
    ushort* __restrict__ qo, ushort* __restrict__ ko_, ushort* __restrict__ vo)
{
    __shared__ ushort smem[40960];   // 80 KB: As 128x128=16384, Bs[3] 64x128=8192 each
    ushort* As  = smem;
    ushort* Bs0 = smem + 16384;
    ushort* Bs1 = smem + 24576;
    ushort* Bs2 = smem + 32768;

    const int lin = blockIdx.x + 16 * blockIdx.y;   // [0,512)
    const int swz = (lin & 7) * 64 + (lin >> 3);    // bijective XCD chunks
    const int bx = swz & 15, by = swz >> 4;

    const int t = threadIdx.x;                      // 0..511
    const int lane = t & 63, wave = t >> 6;         // wave 0..7
    const int col = lane & 15, quad = lane >> 4;
    const int m0 = by * 128, n0 = bx * 64;
    const int wm = (wave & 3) * 32, wn = (wave >> 2) * 32;

    f32x4 acc[3][2][2] = {};

    for (int k0 = 0; k0 < DIM; k0 += 128) {
        __syncthreads();
        #pragma unroll
        for (int j = 0; j < 4; ++j) {               // A: 2048 chunks, 4 issues/wave
            int C = wave * 256 + j * 64 + lane;
            int row = C >> 4;
            int lch = (C & 15) ^ (row & 7);
            async_cp16(&A[(size_t)(m0 + row) * DIM + k0 + lch * 8],
                       &As[(wave * 256 + j * 64) * 8]);
        }
        #pragma unroll
        for (int j = 0; j < 2; ++j) {               // B: 1024 chunks each, 2 issues/wave
            int C = wave * 128 + j * 64 + lane;
            int row = C >> 4;
            int lch = (C & 15) ^ (row & 7);
            size_t goff = (size_t)(n0 + row) * DIM + k0 + lch * 8;
            async_cp16(&WqT[goff], &Bs0[(wave * 128 + j * 64) * 8]);
            async_cp16(&WkT[goff], &Bs1[(wave * 128 + j * 64) * 8]);
            async_cp16(&WvT[goff], &Bs2[(wave * 128 + j * 64) * 8]);
        }
        __syncthreads();
        #pragma unroll
        for (int kk = 0; kk < 4; ++kk) {
            bh8 af[2];
            #pragma unroll
            for (int mi = 0; mi < 2; ++mi) {
                int row = wm + mi * 16 + col;
                af[mi] = *(const bh8*)&As[row * 128 + (((kk * 4 + quad) ^ (row & 7)) * 8)];
            }
            const ushort* Bsz[3] = { Bs0, Bs1, Bs2 };
            #pragma unroll
            for (int z = 0; z < 3; ++z) {
                bh8 bfr[2];
                #pragma unroll
                for (int ni = 0; ni < 2; ++ni) {
                    int row = wn + ni * 16 + col;
                    bfr[ni] = *(const bh8*)&Bsz[z][row * 128 + (((kk * 4 + quad) ^ (row & 7)) * 8)];
                }
                #pragma unroll
                for (int mi = 0; mi < 2; ++mi)
                    #pragma unroll
                    for (int ni = 0; ni < 2; ++ni)
                        acc[z][mi][ni] = MFMA16(af[mi], bfr[ni], acc[z][mi][ni]);
            }
        }
    }

    const int b = m0 >> 11, s0 = m0 & (SEQ - 1);
    const int h = bx;                               // n0>>6

    #pragma unroll
    for (int z = 0; z < 3; ++z) {                   // FULL unroll: static acc[z] index
        const float* bias = (z == 0) ? bq : (z == 1) ? bk : bv;
        ushort* outp = (z == 0) ? qo : (z == 1) ? ko_ : vo;
        __syncthreads();                            // prev phase reads / core reads done
        if (z < 2) {
            const float scl = (z == 0) ? SCALE_Q : 1.f;
            ushort* LT = smem;                      // 128 x 72
            #pragma unroll
            for (int mi = 0; mi < 2; ++mi)
                #pragma unroll
                for (int ni = 0; ni < 2; ++ni) {
                    int dl = wn + ni * 16 + col;
                    float bvv = bias[n0 + dl];
                    #pragma unroll
                    for (int r = 0; r < 4; ++r) {
                        int ml = wm + mi * 16 + quad * 4 + r;
                        LT[ml * 72 + dl] = f2bf((acc[z][mi][ni][r] + bvv) * scl);
                    }
                }
            __syncthreads();
            ushort* Cp = outp + (((size_t)(b * NUM_HEADS + h) * SEQ + s0) << 6);
            #pragma unroll
            for (int i = 0; i < 2; ++i) {
                int c = i * 512 + t;                // 1024 chunks of 8
                int row = c >> 3, ko = (c & 7) * 8;
                *(uint4*)&Cp[row * 64 + ko] = *(const uint4*)&LT[row * 72 + ko];
            }
        } else {
            // V transposed [B,H,64,S] via LDS transpose
            ushort* LT = smem;                      // 64 x 136
            #pragma unroll
            for (int mi = 0; mi < 2; ++mi)
                #pragma unroll
                for (int ni = 0; ni < 2; ++ni) {
                    int nl = wn + ni * 16 + col;
                    float bvv = bias[n0 + nl];
                    #pragma unroll
                    for (int r = 0; r < 4; ++r) {
                        int ml = wm + mi * 16 + quad * 4 + r;
                        LT[nl * 136 + ml] = f2bf(acc[z][mi][ni][r] + bvv);
                    }
                }
            __syncthreads();
            ushort* Cp = outp + (((size_t)(b * NUM_HEADS + h) * HEAD_DIM) << 11);
            #pragma unroll
            for (int i = 0; i < 2; ++i) {
                int c = i * 512 + t;                // 1024 chunks of 8
                int row = c >> 4, mo = (c & 15) * 8;
                *(uint4*)&Cp[((size_t)row << 11) + s0 + mo] = *(const uint4*)&LT[row * 136 + mo];
            }
        }
    }
}

// ---------------- shared MFMA GEMM core: 128x64 tile, BK=64 (R0-proven) ---------------
// R16 lesson: BK=128 here regressed (24->48KB LDS binds residency at 256 threads;
// unlike qkv, which is VGPR-capped). Keep BK=64.
#define GTM 128
#define GTN 64

__device__ __forceinline__ void gemm_core(
    const ushort* __restrict__ A, const ushort* __restrict__ Bt,
    ushort* smem, int m0, int n0, int t, f32x4 acc[4][2])
{
    ushort* As = smem;          // 128*64 = 8192 ushorts
    ushort* Bs = smem + 8192;   //  64*64 = 4096 ushorts
    const int lane = t & 63, wave = t >> 6;
    const int col = lane & 15, quad = lane >> 4;
    const int wm = (wave & 1) * 64, wn = (wave >> 1) * 32;

    for (int k0 = 0; k0 < DIM; k0 += 64) {
        __syncthreads();
        #pragma unroll
        for (int j = 0; j < 4; ++j) {
            int C = wave * 256 + j * 64 + lane;
            int row = C >> 3;
            int lch = (C & 7) ^ (row & 7);
            async_cp16(&A[(size_t)(m0 + row) * DIM + k0 + lch * 8],
                       &As[(wave * 256 + j * 64) * 8]);
        }
        #pragma unroll
        for (int j = 0; j < 2; ++j) {
            int C = wave * 128 + j * 64 + lane;
            int row = C >> 3;
            int lch = (C & 7) ^ (row & 7);
            async_cp16(&Bt[(size_t)(n0 + row) * DIM + k0 + lch * 8],
                       &Bs[(wave * 128 + j * 64) * 8]);
        }
        __syncthreads();
        #pragma unroll
        for (int kk = 0; kk < 2; ++kk) {
            bh8 af[4], bfr[2];
            #pragma unroll
            for (int mi = 0; mi < 4; ++mi) {
                int row = wm + mi * 16 + col;
                af[mi] = *(const bh8*)&As[row * 64 + (((kk * 4 + quad) ^ (row & 7)) * 8)];
            }
            #pragma unroll
            for (int ni = 0; ni < 2; ++ni) {
                int row = wn + ni * 16 + col;
                bfr[ni] = *(const bh8*)&Bs[row * 64 + (((kk * 4 + quad) ^ (row & 7)) * 8)];
            }
            #pragma unroll
            for (int mi = 0; mi < 4; ++mi)
                #pragma unroll
                for (int ni = 0; ni < 2; ++ni)
                    acc[mi][ni] = MFMA16(af[mi], bfr[ni], acc[mi][ni]);
        }
    }
}

// ---------------- output projection: fp32 out (R9-exact, XCD-swizzled) ----------------
__global__ __launch_bounds__(256) void gemm_out(
    const ushort* __restrict__ A, const ushort* __restrict__ Bt,
    const float* __restrict__ bias, float* __restrict__ C)
{
    __shared__ ushort smem[12288];
    const int lin = blockIdx.x + 16 * blockIdx.y;   // [0,512)
    const int swz = (lin & 7) * 64 + (lin >> 3);    // bijective
    const int bx = swz & 15, by = swz >> 4;

    const int t = threadIdx.x;
    const int lane = t & 63, wave = t >> 6;
    const int col = lane & 15, quad = lane >> 4;
    const int m0 = by * GTM, n0 = bx * GTN;
    const int wm = (wave & 1) * 64, wn = (wave >> 1) * 32;
    f32x4 acc[4][2] = {};

    gemm_core(A, Bt, smem, m0, n0, t, acc);

    #pragma unroll
    for (int mi = 0; mi < 4; ++mi)
        #pragma unroll
        for (int ni = 0; ni < 2; ++ni) {
            int n = n0 + wn + ni * 16 + col;
            float bvv = bias[n];
            #pragma unroll
            for (int r = 0; r < 4; ++r) {
                int m = m0 + wm + mi * 16 + quad * 4 + r;
                C[(size_t)m * DIM + n] = acc[mi][ni][r] + bvv;
            }
        }
}

// ---------------- MFMA flash attention: R9-exact (best measured: 48.3-48.8us) --------
__global__ __launch_bounds__(256, 2) void attn_mfma(
    const ushort* __restrict__ Qg, const ushort* __restrict__ Kg,
    const ushort* __restrict__ Vtg, ushort* __restrict__ ctx)
{
    __shared__ char smem[34304];
    float* OA   = (float*)smem;                    // 64x65 f32 = 16640 B
    float* OB   = (float*)(smem + 16640);          // 64x65 f32
    float* lbuf = (float*)(smem + 33280);          // 4x64 f32

    const int t = threadIdx.x;
    const int lane = t & 63, wave = t >> 6;
    const int q32 = lane & 31, h = lane >> 5;      // lane column / half
    const int bh = blockIdx.x & 31;                // fast: bh b -> XCD b%8 (K/V L2-local)
    const int qt = 31 - (blockIdx.x >> 5);         // slow, descending: LPT
    const int b = bh >> 4, hd = bh & 15;
    const int q0 = qt << 6;
    const int kw0 = wave * 32;                     // wave's key offset in 128-span
    const ushort* Kp = Kg + ((size_t)bh << 17);
    const ushort* Vp = Vtg + ((size_t)bh << 17);
    const ushort* Qp = Qg + ((size_t)bh << 17);

    // Q fragments (B-operand): [qti][kc], pre-scaled by 0.125*log2e
    bh8 qf[2][4];
    #pragma unroll
    for (int qti = 0; qti < 2; ++qti)
        #pragma unroll
        for (int kc = 0; kc < 4; ++kc)
            qf[qti][kc] = *(const bh8*)&Qp[((size_t)(q0 + qti * 32 + q32) << 6)
                                           + kc * 16 + h * 8];

    f32x16 O[2][2] = {};                           // [qti][dti]: C col=q, row=d
    float l[2] = {0.f, 0.f};
    const int nIter = (q0 + 191) >> 7;             // ceil((q0+64)/128)

    // prologue: load iter-0 K/V into next-buffers
    bh8 kf_n[4], vf_n[2][2];
    #pragma unroll
    for (int kc = 0; kc < 4; ++kc)
        kf_n[kc] = *(const bh8*)&Kp[((size_t)(kw0 + q32) << 6) + kc * 16 + h * 8];
    #pragma unroll
    for (int dti = 0; dti < 2; ++dti)
        #pragma unroll
        for (int kc = 0; kc < 2; ++kc)
            vf_n[dti][kc] = *(const bh8*)&Vp[((size_t)(dti * 32 + q32) << 11)
                                             + kw0 + kc * 16 + h * 8];

    #pragma unroll 1
    for (int it = 0; it < nIter; ++it) {
        const int kb = it << 7;
        if (kb + kw0 > q0 + 63) break;             // once masked, always masked

        // rotate buffers (register renames, free)
        bh8 kf[4], vf[2][2];
        #pragma unroll
        for (int kc = 0; kc < 4; ++kc) kf[kc] = kf_n[kc];
        #pragma unroll
        for (int dti = 0; dti < 2; ++dti) {
            vf[dti][0] = vf_n[dti][0]; vf[dti][1] = vf_n[dti][1];
        }

        // issue ALL it+1 prefetches NOW -> full-iteration issue->consume distance
        const int kb2 = kb + 128;
        if (it + 1 < nIter) {
            #pragma unroll
            for (int kc = 0; kc < 4; ++kc)
                kf_n[kc] = *(const bh8*)&Kp[((size_t)(kb2 + kw0 + q32) << 6)
                                            + kc * 16 + h * 8];
            #pragma unroll
            for (int dti = 0; dti < 2; ++dti)
                #pragma unroll
                for (int kc = 0; kc < 2; ++kc)
                    vf_n[dti][kc] = *(const bh8*)&Vp[((size_t)(dti * 32 + q32) << 11)
                                                     + kb2 + kw0 + kc * 16 + h * 8];
        }

        // St = K_w @ Q^T per 32-q tile: C col=q32, row=key (r&3)+8*(r>>2)+4h
        f32x16 St[2] = {};
        __builtin_amdgcn_s_setprio(1);
        #pragma unroll
        for (int kc = 0; kc < 4; ++kc) {
            St[0] = MFMA32(kf[kc], qf[0][kc], St[0]);
            St[1] = MFMA32(kf[kc], qf[1][kc], St[1]);
        }
        __builtin_amdgcn_s_setprio(0);

        // causal mask (only near the diagonal)
        if (kb + kw0 + 31 > q0) {
            #pragma unroll
            for (int qti = 0; qti < 2; ++qti) {
                int q_abs = q0 + qti * 32 + q32;
                #pragma unroll
                for (int r = 0; r < 16; ++r) {
                    int key_abs = kb + kw0 + (r & 3) + ((r >> 2) << 3) + 4 * h;
                    if (key_abs > q_abs) St[qti][r] = -1e30f;
                }
            }
        }

        // exp2 (Q pre-scaled) -> pack bf16 -> permlane32_swap -> PV B-operand
        #pragma unroll
        for (int qti = 0; qti < 2; ++qti) {
            float p[16];
            #pragma unroll
            for (int r = 0; r < 16; ++r) p[r] = EXP2F(St[qti][r]);
            float t0 = (p[0] + p[1]) + (p[2] + p[3]);
            float t1 = (p[4] + p[5]) + (p[6] + p[7]);
            float t2 = (p[8] + p[9]) + (p[10] + p[11]);
            float t3 = (p[12] + p[13]) + (p[14] + p[15]);
            l[qti] += (t0 + t1) + (t2 + t3);

            unsigned w[8];
            #pragma unroll
            for (int m = 0; m < 8; ++m) w[m] = cvt_pk_bf16(p[2 * m], p[2 * m + 1]);
            unsigned j0, j1, j2, j3, j4, j5, j6, j7;
            plane_swap(w[0], w[2], j0, j2, h);     // keys 0-15  -> B-words 0..3
            plane_swap(w[1], w[3], j1, j3, h);
            plane_swap(w[4], w[6], j4, j6, h);     // keys 16-31 -> B-words 0..3
            plane_swap(w[5], w[7], j5, j7, h);
            union { unsigned u[4]; bh8 v; } pu0, pu1;
            pu0.u[0] = j0; pu0.u[1] = j1; pu0.u[2] = j2; pu0.u[3] = j3;
            pu1.u[0] = j4; pu1.u[1] = j5; pu1.u[2] = j6; pu1.u[3] = j7;

            // O[qti][dti] += V_w^T @ P (A=V^T from regs, B=P in regs; C col=q, row=d)
            __builtin_amdgcn_s_setprio(1);
            O[qti][0] = MFMA32(vf[0][0], pu0.v, O[qti][0]);
            O[qti][1] = MFMA32(vf[1][0], pu0.v, O[qti][1]);
            O[qti][0] = MFMA32(vf[0][1], pu1.v, O[qti][0]);
            O[qti][1] = MFMA32(vf[1][1], pu1.v, O[qti][1]);
            __builtin_amdgcn_s_setprio(0);
        }
    }

    // ----- epilogue: cross-wave reduction -----
    l[0] += __shfl_xor(l[0], 32);
    l[1] += __shfl_xor(l[1], 32);
    if (lane < 32) {
        lbuf[wave * 64 + q32]      = l[0];
        lbuf[wave * 64 + 32 + q32] = l[1];
    }
    __syncthreads();   // #1: l published

    if (wave == 1 || wave == 3) {
        float* dst = (wave == 1) ? OA : OB;
        #pragma unroll
        for (int qti = 0; qti < 2; ++qti)
            #pragma unroll
            for (int dti = 0; dti < 2; ++dti)
                #pragma unroll
                for (int r = 0; r < 16; ++r) {
                    int d_l = dti * 32 + (r & 3) + ((r >> 2) << 3) + 4 * h;
                    dst[d_l * 65 + qti * 32 + q32] = O[qti][dti][r];
                }
    }
    __syncthreads();   // #2
    if (wave == 0 || wave == 2) {
        float* src = (wave == 0) ? OA : OB;
        #pragma unroll
        for (int qti = 0; qti < 2; ++qti)
            #pragma unroll
            for (int dti = 0; dti < 2; ++dti)
                #pragma unroll
                for (int r = 0; r < 16; ++r) {
                    int d_l = dti * 32 + (r & 3) + ((r >> 2) << 3) + 4 * h;
                    O[qti][dti][r] += src[d_l * 65 + qti * 32 + q32];
                }
    }
    __syncthreads();   // #3
    if (wave == 2) {
        #pragma unroll
        for (int qti = 0; qti < 2; ++qti)
            #pragma unroll
            for (int dti = 0; dti < 2; ++dti)
                #pragma unroll
                for (int r = 0; r < 16; ++r) {
                    int d_l = dti * 32 + (r & 3) + ((r >> 2) << 3) + 4 * h;
                    OA[d_l * 65 + qti * 32 + q32] = O[qti][dti][r];
                }
    }
    __syncthreads();   // #4
    if (wave == 0) {
        float tot0 = lbuf[q32] + lbuf[64 + q32] + lbuf[128 + q32] + lbuf[192 + q32];
        float tot1 = lbuf[32 + q32] + lbuf[96 + q32] + lbuf[160 + q32] + lbuf[224 + q32];
        float inv0 = 1.f / tot0, inv1 = 1.f / tot1;
        ushort* Oq = (ushort*)(smem + 16640);      // 64 x 72 ushorts (reuse OB)
        #pragma unroll
        for (int qti = 0; qti < 2; ++qti) {
            float invq = qti ? inv1 : inv0;
            int qrow = qti * 32 + q32;
            #pragma unroll
            for (int dti = 0; dti < 2; ++dti)
                #pragma unroll
                for (int rg = 0; rg < 4; ++rg) {
                    int d0 = dti * 32 + rg * 8 + 4 * h;
                    float s0 = (O[qti][dti][rg * 4 + 0] + OA[(d0 + 0) * 65 + qrow]) * invq;
                    float s1 = (O[qti][dti][rg * 4 + 1] + OA[(d0 + 1) * 65 + qrow]) * invq;
                    float s2 = (O[qti][dti][rg * 4 + 2] + OA[(d0 + 2) * 65 + qrow]) * invq;
                    float s3 = (O[qti][dti][rg * 4 + 3] + OA[(d0 + 3) * 65 + qrow]) * invq;
                    uint2 pk; pk.x = cvt_pk_bf16(s0, s1); pk.y = cvt_pk_bf16(s2, s3);
                    *(uint2*)&Oq[qrow * 72 + d0] = pk;
                }
        }
        // coalesced 16B stores: 512 chunks of 8 ushorts, 8 per lane
        #pragma unroll
        for (int i = 0; i < 8; ++i) {
            int c = i * 64 + lane;
            int row = c >> 3, ko = (c & 7) * 8;
            *(uint4*)&ctx[((size_t)(b * SEQ) + q0 + row) * DIM + (hd << 6) + ko] =
                *(const uint4*)&Oq[row * 72 + ko];
        }
    }
}

// ---------------- launch ----------------
extern "C" void kernel_launch(void* const* d_in, const int* in_sizes, int n_in,
                              void* d_out, int out_size, void* d_ws, size_t ws_size,
                              hipStream_t stream) {
    const float* x  = (const float*)d_in[0];
    const float* Wq = (const float*)d_in[1];
    const float* bq = (const float*)d_in[2];
    const float* Wk = (const float*)d_in[3];
    const float* bk = (const float*)d_in[4];
    const float* Wv = (const float*)d_in[5];
    const float* bv = (const float*)d_in[6];
    const float* Wo = (const float*)d_in[7];
    const float* bo = (const float*)d_in[8];
    float* out = (float*)d_out;

    ushort* x_bf   = (ushort*)d_ws;              // 4M elems
    ushort* wq_t   = x_bf + 4194304;             // 1M each
    ushort* wk_t   = wq_t + 1048576;
    ushort* wv_t   = wk_t + 1048576;
    ushort* wo_t   = wv_t + 1048576;
    ushort* q_ws   = wo_t + 1048576;             // [B,H,S,64] 4M (pre-scaled)
    ushort* k_ws   = q_ws + 4194304;
    ushort* vt_ws  = k_ws + 4194304;             // [B,H,64,S] 4M
    ushort* ctx_ws = vt_ws + 4194304;            // [B,S,DIM]  4M

    dim3 pgrid(32, 32, 5);
    prep_inputs<<<pgrid, 256, 0, stream>>>(Wq, Wk, Wv, Wo, x,
                                           wq_t, wk_t, wv_t, wo_t, x_bf);

    dim3 qkv_grid(16, 32);                       // 512 blocks, z-fused, BK=128
    gemm_qkv<<<qkv_grid, 512, 0, stream>>>(x_bf, wq_t, wk_t, wv_t,
                                           bq, bk, bv, q_ws, k_ws, vt_ws);

    attn_mfma<<<1024, 256, 0, stream>>>(q_ws, k_ws, vt_ws, ctx_ws);

    dim3 ogrid(DIM / GTN, M_ROWS / GTM);         // (16, 32)
    gemm_out<<<ogrid, 256, 0, stream>>>(ctx_ws, wo_t, bo, out);
}